// Round 2
// baseline (25354.156 us; speedup 1.0000x reference)
//
#include <hip/hip_runtime.h>
#include <hip/hip_bf16.h>

// Problem constants
constexpr int Bn = 256, Tn = 200, Dn = 32, Hn = 512, PHn = 256, PREPn = 16;
constexpr int COVn = 32, COVHn = 128, CLFHn = 64;
constexpr float DTc = 0.05f;

// Packed f16 weight segment offsets (in f16 elements) inside d_ws.
// Layout per matrix [N outputs, K inputs]: elem (k,j) at u16 idx ((k>>3)*N + j)*8 + (k&7)
// i.e. 8 consecutive k-values of one output column per 16B (one uint4).
constexpr int OFF_WHR   = 0;
constexpr int OFF_WHZ   = 262144;
constexpr int OFF_WHH   = 524288;
constexpr int OFF_WP1   = 786432;
constexpr int OFF_WP2   = 917504;
constexpr int OFF_WIH   = 933888;
constexpr int OFF_WHH2  = 1720320;
constexpr int OFF_WCLF1 = 2506752;
constexpr int WS_ELEMS  = 2539520;

typedef _Float16 h2v __attribute__((ext_vector_type(2)));

struct PrepArgs {
  const float* src[8];
  _Float16* dst;
};

__global__ void prep_pack_kernel(PrepArgs a) {
  int idx = blockIdx.x * 256 + threadIdx.x;
  if (idx >= WS_ELEMS) return;
  int s, off, N, K;
  if      (idx < 262144)  { s = 0; off = 0;       N = 512;  K = 512; }
  else if (idx < 524288)  { s = 1; off = 262144;  N = 512;  K = 512; }
  else if (idx < 786432)  { s = 2; off = 524288;  N = 512;  K = 512; }
  else if (idx < 917504)  { s = 3; off = 786432;  N = 256;  K = 512; }
  else if (idx < 933888)  { s = 4; off = 917504;  N = 64;   K = 256; }
  else if (idx < 1720320) { s = 5; off = 933888;  N = 1536; K = 512; }
  else if (idx < 2506752) { s = 6; off = 1720320; N = 1536; K = 512; }
  else                    { s = 7; off = 2506752; N = 64;   K = 512; }
  const int li = idx - off;
  const int r  = li & 7;
  const int t2 = li >> 3;
  const int j  = t2 % N;
  const int k8 = t2 / N;
  a.dst[idx] = (_Float16)(a.src[s][(size_t)j * K + (k8 * 8 + r)]);
}

struct MainArgs {
  const float *cov, *X, *M;
  const float *Wc1, *bc1, *Wc2, *bc2;
  const float *Whr, *Whz, *Whh;
  const float *Wp1, *bp1, *Wp2, *bp2;
  const float *w_prep, *bias_prep;
  const float *W_ih, *W_hh, *b_ih, *b_hh;
  const float *Wclf1, *bclf1, *Wclf2, *bclf2;
  const _Float16* WP;
  float* out;
};

__device__ __forceinline__ float sigmoidf(float x) { return 1.0f / (1.0f + __expf(-x)); }

__device__ __forceinline__ float fdot2(unsigned w, unsigned v, float acc) {
#if __has_builtin(__builtin_amdgcn_fdot2)
  return __builtin_amdgcn_fdot2(__builtin_bit_cast(h2v, w),
                                __builtin_bit_cast(h2v, v), acc, false);
#else
  h2v a = __builtin_bit_cast(h2v, w), b = __builtin_bit_cast(h2v, v);
  return acc + (float)a.x * (float)b.x + (float)a.y * (float)b.y;
#endif
}

__device__ __forceinline__ float dotq(uint4 w, uint4 h, float acc) {
  acc = fdot2(w.x, h.x, acc);
  acc = fdot2(w.y, h.y, acc);
  acc = fdot2(w.z, h.z, acc);
  acc = fdot2(w.w, h.w, acc);
  return acc;
}

__device__ __forceinline__ unsigned pack2(float a, float b) {
  h2v h; h.x = (_Float16)a; h.y = (_Float16)b;
  return __builtin_bit_cast(unsigned, h);
}

// Load one 8-k quad of weights for output column j, quad q.
template<bool PACKED>
__device__ __forceinline__ uint4 ldwq(const uint4* WQ, const float* W,
                                      int N, int K, int q, int j) {
  if constexpr (PACKED) {
    return WQ[(size_t)q * N + j];
  } else {
    const float* p = W + (size_t)j * K + q * 8;
    uint4 r;
    r.x = pack2(p[0], p[1]); r.y = pack2(p[2], p[3]);
    r.z = pack2(p[4], p[5]); r.w = pack2(p[6], p[7]);
    return r;
  }
}

template<bool PACKED>
__global__ __launch_bounds__(512)
void gruode_kernel(MainArgs a) {
  const int b   = blockIdx.x;
  const int tid = threadIdx.x;

  __shared__ __align__(16) uint4 h2q[Hn / 8];    // h as f16 (current)
  __shared__ __align__(16) uint4 rh2q[Hn / 8];   // r*h as f16
  __shared__ __align__(16) uint4 gi2q[Hn / 8];   // gi as f16
  __shared__ __align__(16) uint4 q2q[PHn / 8];   // q as f16
  __shared__ float p_s[2 * Dn];
  __shared__ float t1_s[COVHn];
  __shared__ float xrow_s[Dn], mrow_s[Dn];
  __shared__ float covrow_s[COVn];
  __shared__ int   act_s[Dn];
  __shared__ int   nact_s;

  _Float16* h2  = (_Float16*)h2q;
  _Float16* rh2 = (_Float16*)rh2q;
  _Float16* gi2 = (_Float16*)gi2q;
  _Float16* q2  = (_Float16*)q2q;

  const uint4* WhrQ   = (const uint4*)(a.WP + OFF_WHR);
  const uint4* WhzQ   = (const uint4*)(a.WP + OFF_WHZ);
  const uint4* WhhQ   = (const uint4*)(a.WP + OFF_WHH);
  const uint4* Wp1Q   = (const uint4*)(a.WP + OFF_WP1);
  const uint4* Wp2Q   = (const uint4*)(a.WP + OFF_WP2);
  const uint4* WihQ   = (const uint4*)(a.WP + OFF_WIH);
  const uint4* Whh2Q  = (const uint4*)(a.WP + OFF_WHH2);
  const uint4* Wclf1Q = (const uint4*)(a.WP + OFF_WCLF1);

  // ---- h0 = tanh(relu(cov@Wc1^T + bc1)@Wc2^T + bc2), fp32 ----
  float hreg;
  if (tid < COVn) covrow_s[tid] = a.cov[b * COVn + tid];
  __syncthreads();
  if (tid < COVHn) {
    float acc = a.bc1[tid];
    #pragma unroll
    for (int k = 0; k < COVn; ++k) acc += covrow_s[k] * a.Wc1[tid * COVn + k];
    t1_s[tid] = fmaxf(acc, 0.0f);
  }
  __syncthreads();
  {
    float acc = a.bc2[tid];
    for (int k = 0; k < COVHn; ++k) acc += t1_s[k] * a.Wc2[tid * COVHn + k];
    hreg = tanhf(acc);
    h2[tid] = (_Float16)hreg;
  }
  __syncthreads();

  for (int t = 0; t < Tn; ++t) {
    // ---- A: r = sig(h@Whr^T), z = sig(h@Whz^T); rh = r*h ----
    float zz;
    {
      float sr = 0.0f, sz = 0.0f;
      #pragma unroll 4
      for (int q = 0; q < Hn / 8; ++q) {
        const uint4 hq = h2q[q];
        sr = dotq(ldwq<PACKED>(WhrQ, a.Whr, Hn, Hn, q, tid), hq, sr);
        sz = dotq(ldwq<PACKED>(WhzQ, a.Whz, Hn, Hn, q, tid), hq, sz);
      }
      const float rr = sigmoidf(sr);
      zz = sigmoidf(sz);
      rh2[tid] = (_Float16)(rr * hreg);
    }
    __syncthreads();

    // ---- B: u = tanh(rh@Whh^T); Euler step; publish new h ----
    {
      float su = 0.0f;
      #pragma unroll 4
      for (int q = 0; q < Hn / 8; ++q)
        su = dotq(ldwq<PACKED>(WhhQ, a.Whh, Hn, Hn, q, tid), rh2q[q], su);
      const float u = tanhf(su);
      hreg = hreg + DTc * (1.0f - zz) * (u - hreg);
      h2[tid] = (_Float16)hreg;   // old h2 readers (A, prev G) all behind A's barrier
    }
    __syncthreads();

    // ---- C: q = relu(h@Wp1^T + bp1); side-load X,M rows ----
    if (tid < PHn) {
      float acc = a.bp1[tid];
      #pragma unroll 4
      for (int q = 0; q < Hn / 8; ++q)
        acc = dotq(ldwq<PACKED>(Wp1Q, a.Wp1, PHn, Hn, q, tid), h2q[q], acc);
      q2[tid] = (_Float16)fmaxf(acc, 0.0f);
    } else if (tid >= 448 && tid < 480) {
      const int d = tid - 448;
      mrow_s[d] = a.M[((size_t)t * Bn + b) * Dn + d];
    } else if (tid >= 480) {
      const int d = tid - 480;
      xrow_s[d] = a.X[((size_t)t * Bn + b) * Dn + d];
    }
    __syncthreads();

    // ---- D: p = q@Wp2^T + bp2 ----
    if (tid < 2 * Dn) {
      float acc = a.bp2[tid];
      #pragma unroll
      for (int q = 0; q < PHn / 8; ++q)
        acc = dotq(ldwq<PACKED>(Wp2Q, a.Wp2, 2 * Dn, PHn, q, tid), q2q[q], acc);
      p_s[tid] = acc;
    }
    __syncthreads();

    // ---- E: prep einsum -> gi; build active-feature list ----
    {
      const int d = tid >> 4, pp = tid & 15;
      const float xv   = xrow_s[d];
      const float mean = p_s[d];
      const float logv = p_s[Dn + d];
      const float err  = (xv - mean) * __expf(-0.5f * logv);
      float acc = a.bias_prep[d * PREPn + pp];
      acc += xv   * a.w_prep[(d * 4 + 0) * PREPn + pp];
      acc += mean * a.w_prep[(d * 4 + 1) * PREPn + pp];
      acc += logv * a.w_prep[(d * 4 + 2) * PREPn + pp];
      acc += err  * a.w_prep[(d * 4 + 3) * PREPn + pp];
      gi2[tid] = (_Float16)(fmaxf(acc, 0.0f) * mrow_s[d]);
      if (tid == 0) {
        int n = 0;
        for (int dd = 0; dd < Dn; ++dd)
          if (mrow_s[dd] > 0.0f) act_s[n++] = dd;
        nact_s = n;
      }
    }
    __syncthreads();

    // ---- F: GRUCell gates (r,z,n); only rows with observations update ----
    if (nact_s > 0) {           // block-uniform condition
      float gr = a.b_ih[tid]          + a.b_hh[tid];
      float gz = a.b_ih[Hn + tid]     + a.b_hh[Hn + tid];
      float xn = a.b_ih[2 * Hn + tid];
      float hn = a.b_hh[2 * Hn + tid];
      // dense h-side: 3 gate columns of W_hh
      #pragma unroll 2
      for (int q = 0; q < Hn / 8; ++q) {
        const uint4 hq = h2q[q];
        gr = dotq(ldwq<PACKED>(Whh2Q, a.W_hh, 3 * Hn, Hn, q, tid),          hq, gr);
        gz = dotq(ldwq<PACKED>(Whh2Q, a.W_hh, 3 * Hn, Hn, q, Hn + tid),     hq, gz);
        hn = dotq(ldwq<PACKED>(Whh2Q, a.W_hh, 3 * Hn, Hn, q, 2 * Hn + tid), hq, hn);
      }
      // sparse x-side: only observed feature blocks (gi == 0 elsewhere)
      const int na = nact_s;
      for (int ii = 0; ii < na; ++ii) {
        const int q0 = act_s[ii] * 2;
        #pragma unroll
        for (int qq = 0; qq < 2; ++qq) {
          const int q = q0 + qq;
          const uint4 gq = gi2q[q];
          gr = dotq(ldwq<PACKED>(WihQ, a.W_ih, 3 * Hn, Hn, q, tid),          gq, gr);
          gz = dotq(ldwq<PACKED>(WihQ, a.W_ih, 3 * Hn, Hn, q, Hn + tid),     gq, gz);
          xn = dotq(ldwq<PACKED>(WihQ, a.W_ih, 3 * Hn, Hn, q, 2 * Hn + tid), gq, xn);
        }
      }
      const float rg = sigmoidf(gr);
      const float zg = sigmoidf(gz);
      const float ng = tanhf(xn + rg * hn);
      hreg = (1.0f - zg) * ng + zg * hreg;
      __syncthreads();          // all reads of h2q in this phase done
      h2[tid] = (_Float16)hreg;
    }
    __syncthreads();

    // ---- G: classifier pred = relu(h@Wclf1^T+b)@Wclf2^T + b (wave 0) ----
    if (tid < CLFHn) {
      float acc = a.bclf1[tid];
      #pragma unroll 2
      for (int q = 0; q < Hn / 8; ++q)
        acc = dotq(ldwq<PACKED>(Wclf1Q, a.Wclf1, CLFHn, Hn, q, tid), h2q[q], acc);
      float c = fmaxf(acc, 0.0f) * a.Wclf2[tid];
      #pragma unroll
      for (int off = 32; off > 0; off >>= 1) c += __shfl_down(c, off, 64);
      if (tid == 0) a.out[t * Bn + b] = c + a.bclf2[0];
    }
    // no barrier: next writer of h2/rh2 is behind phase A's barrier
  }
}

extern "C" void kernel_launch(void* const* d_in, const int* in_sizes, int n_in,
                              void* d_out, int out_size, void* d_ws, size_t ws_size,
                              hipStream_t stream) {
  MainArgs a;
  a.cov  = (const float*)d_in[0];
  a.X    = (const float*)d_in[1];
  a.M    = (const float*)d_in[2];
  a.Wc1  = (const float*)d_in[3];  a.bc1 = (const float*)d_in[4];
  a.Wc2  = (const float*)d_in[5];  a.bc2 = (const float*)d_in[6];
  a.Whr  = (const float*)d_in[7];  a.Whz = (const float*)d_in[8];  a.Whh = (const float*)d_in[9];
  a.Wp1  = (const float*)d_in[10]; a.bp1 = (const float*)d_in[11];
  a.Wp2  = (const float*)d_in[12]; a.bp2 = (const float*)d_in[13];
  a.w_prep = (const float*)d_in[14]; a.bias_prep = (const float*)d_in[15];
  a.W_ih = (const float*)d_in[16]; a.W_hh = (const float*)d_in[17];
  a.b_ih = (const float*)d_in[18]; a.b_hh = (const float*)d_in[19];
  a.Wclf1 = (const float*)d_in[20]; a.bclf1 = (const float*)d_in[21];
  a.Wclf2 = (const float*)d_in[22]; a.bclf2 = (const float*)d_in[23];
  a.WP  = (const _Float16*)d_ws;
  a.out = (float*)d_out;

  const bool packed = ws_size >= (size_t)WS_ELEMS * sizeof(_Float16);
  if (packed) {
    PrepArgs p;
    p.src[0] = a.Whr;  p.src[1] = a.Whz;  p.src[2] = a.Whh;  p.src[3] = a.Wp1;
    p.src[4] = a.Wp2;  p.src[5] = a.W_ih; p.src[6] = a.W_hh; p.src[7] = a.Wclf1;
    p.dst = (_Float16*)d_ws;
    prep_pack_kernel<<<(WS_ELEMS + 255) / 256, 256, 0, stream>>>(p);
    gruode_kernel<true><<<Bn, Hn, 0, stream>>>(a);
  } else {
    gruode_kernel<false><<<Bn, Hn, 0, stream>>>(a);
  }
}